// Round 12
// baseline (382.354 us; speedup 1.0000x reference)
//
#include <hip/hip_runtime.h>
#include <math.h>

#define NB 256     // batch
#define IC 1152    // input capsules
#define OC 10      // output capsules
#define OU 16      // output units
#define IK 8       // input units
#define KTOT (IC * IK)        // 9216
#define NTOT (OC * OU)        // 160
#define S_KS 16               // s-pass K-splits (576 k = 18 MFMA each)

typedef __attribute__((ext_vector_type(8))) short short8;
typedef __attribute__((ext_vector_type(4))) float f32x4;

static __device__ __forceinline__ unsigned short f2bf(float f) {
    unsigned u = __float_as_uint(f);
    unsigned r = (u + 0x7FFF + ((u >> 16) & 1)) >> 16;   // RNE
    return (unsigned short)r;
}

// ---- prep: zero blog+counters, inp -> bf16 [256][9216] + transpose [9216][256]
__global__ __launch_bounds__(256) void prep_kernel(
    const float* __restrict__ inp,
    float* __restrict__ blog,
    unsigned short* __restrict__ inpb,   // [256][9216]
    unsigned short* __restrict__ inpT,   // [9216][256]
    int* __restrict__ cnt)               // [3*160]
{
    const int kt  = blockIdx.x;      // 0..143
    const int bt  = blockIdx.y;      // 0..3
    const int tid = threadIdx.x;

    {
        int bid = blockIdx.y * 144 + blockIdx.x;
        if (bid < 45) blog[bid * 256 + tid] = 0.f;
        if (bid >= 100 && bid < 102) {
            int q = (bid - 100) * 256 + tid;
            if (q < 480) cnt[q] = 0;
        }
    }

    __shared__ unsigned short sh[64][65];

#pragma unroll
    for (int j = 0; j < 4; ++j) {
        int q     = j * 256 + tid;
        int b_loc = q >> 4;
        int kq    = (q & 15) * 4;
        float4 g = *(const float4*)&inp[(size_t)(bt * 64 + b_loc) * KTOT + kt * 64 + kq];
        unsigned short h0 = f2bf(g.x), h1 = f2bf(g.y), h2 = f2bf(g.z), h3 = f2bf(g.w);
        sh[kq][b_loc] = h0; sh[kq + 1][b_loc] = h1;
        sh[kq + 2][b_loc] = h2; sh[kq + 3][b_loc] = h3;
        short4 pk = { (short)h0, (short)h1, (short)h2, (short)h3 };
        *(short4*)&inpb[(size_t)(bt * 64 + b_loc) * KTOT + kt * 64 + kq] = pk;
    }
    __syncthreads();

#pragma unroll
    for (int j = 0; j < 4; ++j) {
        int q     = j * 256 + tid;
        int k_loc = q >> 4;
        int b4    = (q & 15) * 4;
        short4 pk = { (short)sh[k_loc][b4],     (short)sh[k_loc][b4 + 1],
                      (short)sh[k_loc][b4 + 2], (short)sh[k_loc][b4 + 3] };
        *(short4*)&inpT[(size_t)(kt * 64 + k_loc) * 256 + bt * 64 + b4] = pk;
    }
}

// ---- s-pass via MFMA, softmax+Wc fused; last-arriving wave per (mt,nt) tile
//      reduces the 16 k-split partials, squashes, writes vout + bf16 vT. ----
#define BLP 584   // B-tile row pitch in shorts (576 + 8 pad)
__global__ __launch_bounds__(256) void spass_kernel(
    const unsigned short* __restrict__ inpb,  // [256][9216]
    const float* __restrict__ W,              // [1152][10][16][8]
    const float* __restrict__ blog,           // [1152][10]
    float* __restrict__ part,                 // [16][256][160]
    float* __restrict__ vout,                 // [256][160]
    unsigned short* __restrict__ vT,          // [160][256]
    int* __restrict__ cnt)                    // [160] for this iteration
{
    const int bid  = blockIdx.x;
    const int nt   = bid % 10;           // output capsule o
    const int ks   = (bid / 10) % 16;    // k-split
    const int mtg  = bid / 160;          // 0..3
    const int tid  = threadIdx.x;
    const int w    = tid >> 6;           // wave 0..3
    const int lane = tid & 63;
    const int l15  = lane & 15;
    const int koff = (lane >> 4) * 8;
    const int k0   = ks * 576;
    const int i0   = ks * 72;
    const int mt   = mtg * 4 + w;

    __shared__ unsigned short Bl[16 * BLP];   // 18.7 KB
    __shared__ float c_loc[72];

    if (tid < 72) {
        const float* br = &blog[(size_t)(i0 + tid) * OC];
        float x[OC], m = -1e30f;
#pragma unroll
        for (int o = 0; o < OC; ++o) { x[o] = br[o]; m = fmaxf(m, x[o]); }
        float ssum = 0.f;
#pragma unroll
        for (int o = 0; o < OC; ++o) ssum += expf(x[o] - m);
        c_loc[tid] = expf(x[nt] - m) / ssum;
    }
    __syncthreads();

#pragma unroll
    for (int jj = 0; jj < 5; ++jj) {
        int q = jj * 256 + tid;          // (i_loc, u) pairs: 72*16 = 1152
        if (q < 1152) {
            int i_loc = q >> 4, u = q & 15;
            const float* wr = W + (((size_t)(i0 + i_loc) * OC + nt) * OU + u) * IK;
            float4 a = *(const float4*)wr;
            float4 b = *(const float4*)(wr + 4);
            float cc = c_loc[i_loc];
            union { short8 v; unsigned short us[8]; } pk;
            pk.us[0] = f2bf(cc * a.x); pk.us[1] = f2bf(cc * a.y);
            pk.us[2] = f2bf(cc * a.z); pk.us[3] = f2bf(cc * a.w);
            pk.us[4] = f2bf(cc * b.x); pk.us[5] = f2bf(cc * b.y);
            pk.us[6] = f2bf(cc * b.z); pk.us[7] = f2bf(cc * b.w);
            *(short8*)&Bl[u * BLP + i_loc * 8] = pk.v;
        }
    }
    __syncthreads();

    const unsigned short* ap  = inpb + (size_t)(mt * 16 + l15) * KTOT + k0 + koff;
    const unsigned short* bls = &Bl[l15 * BLP + koff];

    f32x4 acc = {0.f, 0.f, 0.f, 0.f};
#pragma unroll
    for (int kk = 0; kk < 18; ++kk) {
        short8 av = *(const short8*)(ap + kk * 32);
        short8 bv = *(const short8*)(bls + kk * 32);
        acc = __builtin_amdgcn_mfma_f32_16x16x32_bf16(av, bv, acc, 0, 0, 0);
    }

    float* pp = part + ((size_t)ks * NB + mt * 16 + (lane >> 4) * 4) * NTOT + nt * 16 + l15;
#pragma unroll
    for (int r = 0; r < 4; ++r)
        pp[(size_t)r * NTOT] = acc[r];

    // ---- last-arriver reduction for tile (mt, nt) ----
    __threadfence();                       // release: partial slice visible
    int old = 0;
    if (lane == 0) old = atomicAdd(&cnt[mt * 10 + nt], 1);
    old = __shfl(old, 0);
    if (old == S_KS - 1) {
        __threadfence();                   // acquire: see all 16 slices
        const int bl = l15;                // b-local 0..15
        const int ug = lane >> 4;          // u-group: u = ug*4 + j
        const float* pr = part + (size_t)(mt * 16 + bl) * NTOT + nt * 16 + ug * 4;
        float4 s4 = {0.f, 0.f, 0.f, 0.f};
#pragma unroll
        for (int k2 = 0; k2 < S_KS; ++k2) {
            float4 p4 = *(const float4*)(pr + (size_t)k2 * (NB * NTOT));
            s4.x += p4.x; s4.y += p4.y; s4.z += p4.z; s4.w += p4.w;
        }
        float sq = s4.x * s4.x + s4.y * s4.y + s4.z * s4.z + s4.w * s4.w;
        sq += __shfl_xor(sq, 16);
        sq += __shfl_xor(sq, 32);          // all 4 u-groups of this b
        float alpha = sq / ((1.f + sq) * sqrtf(sq + 1e-9f));
        float4 v4 = { s4.x * alpha, s4.y * alpha, s4.z * alpha, s4.w * alpha };
        *(float4*)&vout[(size_t)(mt * 16 + bl) * NTOT + nt * 16 + ug * 4] = v4;
        unsigned short* vt = vT + (size_t)(nt * 16 + ug * 4) * 256 + mt * 16 + bl;
        vt[0]   = f2bf(v4.x);
        vt[256] = f2bf(v4.y);
        vt[512] = f2bf(v4.z);
        vt[768] = f2bf(v4.w);
    }
}

// ---- delta via MFMA: G[ik][ou] = sum_b inpT[ik][b]*vT[ou][b], fused W-contraction
__global__ __launch_bounds__(256) void delta_kernel(
    const unsigned short* __restrict__ inpT,  // [9216][256]
    const unsigned short* __restrict__ vT,    // [160][256]
    const float* __restrict__ W,              // [1152][10][16][8]
    float* __restrict__ blog)                 // [1152][10] accum
{
    const int g    = blockIdx.x * 4 + (threadIdx.x >> 6);
    const int lane = threadIdx.x & 63;
    const int mt   = g % 576;
    const int nt   = g / 576;           // = o
    const int l15  = lane & 15;
    const int quad = lane >> 4;
    const int koff = quad * 8;

    const unsigned short* ap = inpT + (size_t)(mt * 16 + l15) * 256 + koff;
    const unsigned short* bp = vT   + (size_t)(nt * 16 + l15) * 256 + koff;

    f32x4 acc = {0.f, 0.f, 0.f, 0.f};
#pragma unroll
    for (int kk = 0; kk < 8; ++kk) {
        short8 av = *(const short8*)(ap + kk * 32);
        short8 bv = *(const short8*)(bp + kk * 32);
        acc = __builtin_amdgcn_mfma_f32_16x16x32_bf16(av, bv, acc, 0, 0, 0);
    }

    const int i = mt * 2 + (quad >> 1);
    const float* wr = W + (((size_t)i * OC + nt) * OU + l15) * IK + (quad & 1) * 4;
    float4 wf = *(const float4*)wr;
    float wsum = wf.x * acc[0] + wf.y * acc[1] + wf.z * acc[2] + wf.w * acc[3];

    wsum += __shfl_xor(wsum, 16);
    wsum += __shfl_xor(wsum, 1);
    wsum += __shfl_xor(wsum, 2);
    wsum += __shfl_xor(wsum, 4);
    wsum += __shfl_xor(wsum, 8);

    if ((lane & 31) == 0)
        blog[(size_t)i * OC + nt] += wsum * (1.0f / NB);
}

extern "C" void kernel_launch(void* const* d_in, const int* in_sizes, int n_in,
                              void* d_out, int out_size, void* d_ws, size_t ws_size,
                              hipStream_t stream) {
    const float* inp = (const float*)d_in[0];   // [256][1152][8]
    const float* W   = (const float*)d_in[1];   // [1152][10][16][8]
    float* vout = (float*)d_out;                // [256][10][16]

    float* blog = (float*)d_ws;                              // 11,520 f
    float* part = blog + IC * OC;                            // 655,360 f
    unsigned short* inpb = (unsigned short*)(part + (size_t)S_KS * NB * NTOT);
    unsigned short* inpT = inpb + (size_t)NB * KTOT;         // 2,359,296 u16
    unsigned short* vT   = inpT + (size_t)KTOT * 256;        // 40,960 u16
    int* cnt = (int*)(vT + (size_t)NTOT * 256);              // 480 int

    prep_kernel<<<dim3(144, 4), dim3(256), 0, stream>>>(inp, blog, inpb, inpT, cnt);

    spass_kernel<<<dim3(640), dim3(256), 0, stream>>>(inpb, W, blog, part, vout, vT, cnt);
    delta_kernel<<<dim3(1440), dim3(256), 0, stream>>>(inpT, vT, W, blog);
    spass_kernel<<<dim3(640), dim3(256), 0, stream>>>(inpb, W, blog, part, vout, vT, cnt + 160);
    delta_kernel<<<dim3(1440), dim3(256), 0, stream>>>(inpT, vT, W, blog);
    spass_kernel<<<dim3(640), dim3(256), 0, stream>>>(inpb, W, blog, part, vout, vT, cnt + 320);
}

// Round 13
// 127.855 us; speedup vs baseline: 2.9905x; 2.9905x over previous
//
#include <hip/hip_runtime.h>
#include <math.h>

#define NB 256     // batch
#define IC 1152    // input capsules
#define OC 10      // output capsules
#define OU 16      // output units
#define IK 8       // input units
#define KTOT (IC * IK)        // 9216
#define NTOT (OC * OU)        // 160
#define S_KS 16               // s-pass K-splits (576 k = 18 MFMA each)

typedef __attribute__((ext_vector_type(8))) short short8;
typedef __attribute__((ext_vector_type(4))) float f32x4;

static __device__ __forceinline__ unsigned short f2bf(float f) {
    unsigned u = __float_as_uint(f);
    unsigned r = (u + 0x7FFF + ((u >> 16) & 1)) >> 16;   // RNE
    return (unsigned short)r;
}

// ---- prep: zero blog + inp -> bf16 [256][9216] AND bf16 transpose [9216][256]
__global__ __launch_bounds__(256) void prep_kernel(
    const float* __restrict__ inp,
    float* __restrict__ blog,
    unsigned short* __restrict__ inpb,   // [256][9216]
    unsigned short* __restrict__ inpT)   // [9216][256]
{
    const int kt  = blockIdx.x;      // 0..143
    const int bt  = blockIdx.y;      // 0..3
    const int tid = threadIdx.x;

    {
        int bid = blockIdx.y * 144 + blockIdx.x;
        if (bid < 45) blog[bid * 256 + tid] = 0.f;
    }

    __shared__ unsigned short sh[64][65];

#pragma unroll
    for (int j = 0; j < 4; ++j) {
        int q     = j * 256 + tid;
        int b_loc = q >> 4;
        int kq    = (q & 15) * 4;
        float4 g = *(const float4*)&inp[(size_t)(bt * 64 + b_loc) * KTOT + kt * 64 + kq];
        unsigned short h0 = f2bf(g.x), h1 = f2bf(g.y), h2 = f2bf(g.z), h3 = f2bf(g.w);
        sh[kq][b_loc] = h0; sh[kq + 1][b_loc] = h1;
        sh[kq + 2][b_loc] = h2; sh[kq + 3][b_loc] = h3;
        short4 pk = { (short)h0, (short)h1, (short)h2, (short)h3 };
        *(short4*)&inpb[(size_t)(bt * 64 + b_loc) * KTOT + kt * 64 + kq] = pk;
    }
    __syncthreads();

#pragma unroll
    for (int j = 0; j < 4; ++j) {
        int q     = j * 256 + tid;
        int k_loc = q >> 4;
        int b4    = (q & 15) * 4;
        short4 pk = { (short)sh[k_loc][b4],     (short)sh[k_loc][b4 + 1],
                      (short)sh[k_loc][b4 + 2], (short)sh[k_loc][b4 + 3] };
        *(short4*)&inpT[(size_t)(kt * 64 + k_loc) * 256 + bt * 64 + b4] = pk;
    }
}

// ---- s-pass via MFMA, softmax+Wc fused in-block (R10-verified) ----------
#define BLP 584   // B-tile row pitch in shorts (576 + 8 pad)
__global__ __launch_bounds__(256) void spass_kernel(
    const unsigned short* __restrict__ inpb,  // [256][9216]
    const float* __restrict__ W,              // [1152][10][16][8]
    const float* __restrict__ blog,           // [1152][10]
    float* __restrict__ part)                 // [16][256][160]
{
    const int bid  = blockIdx.x;
    const int nt   = bid % 10;           // output capsule o
    const int ks   = (bid / 10) % 16;    // k-split
    const int mtg  = bid / 160;          // 0..3
    const int tid  = threadIdx.x;
    const int w    = tid >> 6;           // wave 0..3
    const int lane = tid & 63;
    const int l15  = lane & 15;
    const int koff = (lane >> 4) * 8;
    const int k0   = ks * 576;
    const int i0   = ks * 72;
    const int mt   = mtg * 4 + w;

    __shared__ unsigned short Bl[16 * BLP];   // 18.7 KB
    __shared__ float c_loc[72];

    if (tid < 72) {
        const float* br = &blog[(size_t)(i0 + tid) * OC];
        float x[OC], m = -1e30f;
#pragma unroll
        for (int o = 0; o < OC; ++o) { x[o] = br[o]; m = fmaxf(m, x[o]); }
        float ssum = 0.f;
#pragma unroll
        for (int o = 0; o < OC; ++o) ssum += expf(x[o] - m);
        c_loc[tid] = expf(x[nt] - m) / ssum;
    }
    __syncthreads();

#pragma unroll
    for (int jj = 0; jj < 5; ++jj) {
        int q = jj * 256 + tid;          // (i_loc, u) pairs: 72*16 = 1152
        if (q < 1152) {
            int i_loc = q >> 4, u = q & 15;
            const float* wr = W + (((size_t)(i0 + i_loc) * OC + nt) * OU + u) * IK;
            float4 a = *(const float4*)wr;
            float4 b = *(const float4*)(wr + 4);
            float cc = c_loc[i_loc];
            union { short8 v; unsigned short us[8]; } pk;
            pk.us[0] = f2bf(cc * a.x); pk.us[1] = f2bf(cc * a.y);
            pk.us[2] = f2bf(cc * a.z); pk.us[3] = f2bf(cc * a.w);
            pk.us[4] = f2bf(cc * b.x); pk.us[5] = f2bf(cc * b.y);
            pk.us[6] = f2bf(cc * b.z); pk.us[7] = f2bf(cc * b.w);
            *(short8*)&Bl[u * BLP + i_loc * 8] = pk.v;
        }
    }
    __syncthreads();

    const unsigned short* ap  = inpb + (size_t)(mt * 16 + l15) * KTOT + k0 + koff;
    const unsigned short* bls = &Bl[l15 * BLP + koff];

    f32x4 acc = {0.f, 0.f, 0.f, 0.f};
#pragma unroll
    for (int kk = 0; kk < 18; ++kk) {
        short8 av = *(const short8*)(ap + kk * 32);
        short8 bv = *(const short8*)(bls + kk * 32);
        acc = __builtin_amdgcn_mfma_f32_16x16x32_bf16(av, bv, acc, 0, 0, 0);
    }

    float* pp = part + ((size_t)ks * NB + mt * 16 + (lane >> 4) * 4) * NTOT + nt * 16 + l15;
#pragma unroll
    for (int r = 0; r < 4; ++r)
        pp[(size_t)r * NTOT] = acc[r];
}

// ---- reduce partials + squash -> v (fp32) and vT (bf16, transposed) ------
__global__ __launch_bounds__(256) void reduce_squash_kernel(
    const float* __restrict__ part, float* __restrict__ vout,
    unsigned short* __restrict__ vT)   // [160][256]
{
    const int tid = threadIdx.x;
    const int el  = tid & 31;
    const int kl  = tid >> 5;        // 0..7
    const int e   = blockIdx.x * 32 + el;

    float a = part[(size_t)(kl * 2) * (NB * NTOT) + e]
            + part[(size_t)(kl * 2 + 1) * (NB * NTOT) + e];

    __shared__ float red[8][36];
    red[kl][el] = a;
    __syncthreads();

    if (tid < 32) {
        float s = ((red[0][el] + red[1][el]) + (red[2][el] + red[3][el]))
                + ((red[4][el] + red[5][el]) + (red[6][el] + red[7][el]));
        float sq = s * s;
        sq += __shfl_xor(sq, 1);
        sq += __shfl_xor(sq, 2);
        sq += __shfl_xor(sq, 4);
        sq += __shfl_xor(sq, 8);
        float vv = s * (sq / ((1.f + sq) * sqrtf(sq + 1e-9f)));
        vout[e] = vv;
        int n = e % NTOT, b = e / NTOT;
        vT[(size_t)n * 256 + b] = f2bf(vv);
    }
}

// ---- delta via MFMA, 2 nt per wave: G[ik][ou] = sum_b inpT[ik][b]*vT[ou][b]
// 2880 waves = 720 blocks; wave g -> mt = g%576, nt pair = (g/576)*2 + {0,1}.
// A-fragment loaded once, reused for both nt. One writer per (i,o), no atomics.
__global__ __launch_bounds__(256) void delta_kernel(
    const unsigned short* __restrict__ inpT,  // [9216][256]
    const unsigned short* __restrict__ vT,    // [160][256]
    const float* __restrict__ W,              // [1152][10][16][8]
    float* __restrict__ blog)                 // [1152][10] accum
{
    const int g    = blockIdx.x * 4 + (threadIdx.x >> 6);
    const int lane = threadIdx.x & 63;
    const int mt   = g % 576;
    const int ntp  = g / 576;           // 0..4 -> nt = ntp*2, ntp*2+1
    const int l15  = lane & 15;
    const int quad = lane >> 4;
    const int koff = quad * 8;
    const int nt0  = ntp * 2;

    const unsigned short* ap  = inpT + (size_t)(mt * 16 + l15) * 256 + koff;
    const unsigned short* bp0 = vT   + (size_t)(nt0 * 16 + l15) * 256 + koff;
    const unsigned short* bp1 = bp0 + 16 * 256;

    f32x4 acc0 = {0.f, 0.f, 0.f, 0.f};
    f32x4 acc1 = {0.f, 0.f, 0.f, 0.f};
#pragma unroll
    for (int kk = 0; kk < 8; ++kk) {
        short8 av = *(const short8*)(ap  + kk * 32);
        short8 b0 = *(const short8*)(bp0 + kk * 32);
        short8 b1 = *(const short8*)(bp1 + kk * 32);
        acc0 = __builtin_amdgcn_mfma_f32_16x16x32_bf16(av, b0, acc0, 0, 0, 0);
        acc1 = __builtin_amdgcn_mfma_f32_16x16x32_bf16(av, b1, acc1, 0, 0, 0);
    }

    // lane holds G[m=quad*4+r][n=l15]; m -> i_loc = quad>>1, k=(quad&1)*4+r; n -> u
    const int i = mt * 2 + (quad >> 1);
    const float* wr0 = W + (((size_t)i * OC + nt0) * OU + l15) * IK + (quad & 1) * 4;
    float4 wf0 = *(const float4*)wr0;
    float4 wf1 = *(const float4*)(wr0 + OU * IK);   // nt0+1 is adjacent in W
    float w0 = wf0.x * acc0[0] + wf0.y * acc0[1] + wf0.z * acc0[2] + wf0.w * acc0[3];
    float w1 = wf1.x * acc1[0] + wf1.y * acc1[1] + wf1.z * acc1[2] + wf1.w * acc1[3];

#pragma unroll
    for (int d = 0; d < 5; ++d) {
        int m = (d == 0) ? 16 : (1 << (d - 1));   // 16, 1, 2, 4, 8
        w0 += __shfl_xor(w0, m);
        w1 += __shfl_xor(w1, m);
    }

    if ((lane & 31) == 0) {
        blog[(size_t)i * OC + nt0]     += w0 * (1.0f / NB);
        blog[(size_t)i * OC + nt0 + 1] += w1 * (1.0f / NB);
    }
}

extern "C" void kernel_launch(void* const* d_in, const int* in_sizes, int n_in,
                              void* d_out, int out_size, void* d_ws, size_t ws_size,
                              hipStream_t stream) {
    const float* inp = (const float*)d_in[0];   // [256][1152][8]
    const float* W   = (const float*)d_in[1];   // [1152][10][16][8]
    float* vout = (float*)d_out;                // [256][10][16]

    float* blog = (float*)d_ws;                              // 11,520 f
    float* part = blog + IC * OC;                            // 655,360 f
    unsigned short* inpb = (unsigned short*)(part + (size_t)S_KS * NB * NTOT);
    unsigned short* inpT = inpb + (size_t)NB * KTOT;         // 2,359,296 u16
    unsigned short* vT   = inpT + (size_t)KTOT * 256;        // 40,960 u16

    prep_kernel<<<dim3(144, 4), dim3(256), 0, stream>>>(inp, blog, inpb, inpT);

    for (int t = 0; t < 3; ++t) {
        spass_kernel<<<dim3(640), dim3(256), 0, stream>>>(inpb, W, blog, part);
        reduce_squash_kernel<<<dim3(NB * NTOT / 32), dim3(256), 0, stream>>>(part, vout, vT);
        if (t < 2)   // final-iteration b update is dead code in the reference
            delta_kernel<<<dim3(720), dim3(256), 0, stream>>>(inpT, vT, W, blog);
    }
}